// Round 11
// baseline (548.706 us; speedup 1.0000x reference)
//
#include <hip/hip_runtime.h>

// Dynamic per-group (G=128) asymmetric int8 fake-quantize, fp32 in/out.
// Round 11 = best-known kernel (r3 structure) + COPY PROBE for the platform's
// achievable mixed R+W stream rate under identical harness conditions.
// Probe reads cold poisoned ws (untouched by K1) and writes ws — its rocprof
// row (hbm_gbps) tells us whether ~2.5 TB/s is the mixed-stream ceiling
// (-> roofline) or ~6 TB/s is achievable (-> restructure main kernel).

typedef float f32x4 __attribute__((ext_vector_type(4)));

constexpr float QMIN = -128.0f;
constexpr float QMAX = 127.0f;
constexpr float EPSF = 1.1920928955078125e-07f;  // fp32 eps

__device__ __forceinline__ float min4(f32x4 v) {
  return fminf(fminf(v.x, v.y), fminf(v.z, v.w));
}
__device__ __forceinline__ float max4(f32x4 v) {
  return fmaxf(fmaxf(v.x, v.y), fmaxf(v.z, v.w));
}

// Main kernel: 16 consecutive lanes own one group (128 floats = 32 float4s);
// each lane loads float4 #l and #(l+16); 4-level shfl_xor butterfly.
__global__ __launch_bounds__(256) void dsq_kernel(
    const float* __restrict__ x, float* __restrict__ out, int n8) {
  const f32x4* __restrict__ x4 = reinterpret_cast<const f32x4*>(x);
  f32x4* __restrict__ o4 = reinterpret_cast<f32x4*>(out);

  int t = blockIdx.x * blockDim.x + threadIdx.x;
  int nthreads = gridDim.x * blockDim.x;

  for (int p = t; p < n8; p += nthreads) {
    int i0 = ((p >> 4) << 5) + (p & 15);
    f32x4 v0 = x4[i0];
    f32x4 v1 = x4[i0 + 16];

    float mn = fminf(min4(v0), min4(v1));
    float mx = fmaxf(max4(v0), max4(v1));

    #pragma unroll
    for (int m = 1; m < 16; m <<= 1) {
      mn = fminf(mn, __shfl_xor(mn, m, 64));
      mx = fmaxf(mx, __shfl_xor(mx, m, 64));
    }

    mn = fminf(mn, 0.0f);  // observer always includes zero
    mx = fmaxf(mx, 0.0f);

    float scale = fmaxf((mx - mn) * (1.0f / 255.0f), EPSF);
    float inv = 1.0f / scale;  // the only divide
    float zp = fminf(fmaxf(rintf(fmaf(-mn, inv, QMIN)), QMIN), QMAX);
    float nzs = -zp * scale;  // dequant: o = fma(q, scale, nzs)

    f32x4 o0, o1;
    #define QDQ(e) fmaf(fminf(fmaxf(rintf((e) * inv) + zp, QMIN), QMAX), scale, nzs)
    o0.x = QDQ(v0.x); o0.y = QDQ(v0.y); o0.z = QDQ(v0.z); o0.w = QDQ(v0.w);
    o1.x = QDQ(v1.x); o1.y = QDQ(v1.y); o1.z = QDQ(v1.z); o1.w = QDQ(v1.w);
    #undef QDQ

    __builtin_nontemporal_store(o0, &o4[i0]);
    __builtin_nontemporal_store(o1, &o4[i0 + 16]);
  }
}

// Diagnostic probe: pure float4 copy, 256 MiB R + 256 MiB W, cold source
// (first 256 MiB of ws, poison-filled, never touched by dsq_kernel).
__global__ __launch_bounds__(256) void copy_probe(
    const f32x4* __restrict__ src, f32x4* __restrict__ dst, int n4) {
  int t = blockIdx.x * blockDim.x + threadIdx.x;
  int nthreads = gridDim.x * blockDim.x;
  for (int i = t; i < n4; i += nthreads) {
    dst[i] = src[i];
  }
}

extern "C" void kernel_launch(void* const* d_in, const int* in_sizes, int n_in,
                              void* d_out, int out_size, void* d_ws, size_t ws_size,
                              hipStream_t stream) {
  const float* x = (const float*)d_in[0];
  float* out = (float*)d_out;
  int n8 = out_size / 8;  // 8 floats per thread-iteration

  // 1) real kernel (first: sees the same cache state as previous rounds)
  dsq_kernel<<<2048, 256, 0, stream>>>(x, out, n8);

  // 2) probe: copy ws[0:256MiB] -> ws[256MiB:512MiB] (ws is 1 GiB scratch)
  const f32x4* src = (const f32x4*)d_ws;
  f32x4* dst = (f32x4*)((char*)d_ws + (size_t)268435456);
  int n4p = 268435456 / 16;  // 16M float4s
  copy_probe<<<2048, 256, 0, stream>>>(src, dst, n4p);
}